// Round 2
// baseline (339.658 us; speedup 1.0000x reference)
//
#include <hip/hip_runtime.h>
#include <hip/hip_bf16.h>

// ---------------------------------------------------------------------------
// Causal MHA forward.  B=2, T=2048, H=16, Dk=64, D=1024.
// Harness dtype is ambiguous (fp32 reference, bf16-style threshold), so every
// kernel detects input dtype at runtime from X's bit patterns and branches
// (wave-uniform).  Internal pipeline is always bf16 MFMA.
//
// Workspace (u16 elements, 1M = 2^20), total 34 MB:
//   [0,1M)  Wq^T   [1M,2M) Wk^T   [2M,3M) Wv^T   [3M,4M) pad
//   [4M,8M)  Q  [4096][1024]
//   [8M,12M) K  [4096][1024]
//   [12M,16M) V^T [32 bh][64 d][2048 t]
//   [16M,17M) Wo^T
//   Ab [4096][1024] aliases [0,4M)  (Wq^T/Wk^T/Wv^T dead by attention time)
// ---------------------------------------------------------------------------

typedef unsigned short u16;
typedef __bf16 bf16x8 __attribute__((ext_vector_type(8)));
typedef float f32x4 __attribute__((ext_vector_type(4)));

#define TS 72            // LDS row stride (bf16 elems): 144 B, 16B-aligned rows
#define NEG_INF (-1e30f)

__device__ __forceinline__ bf16x8 as_bf16x8(int4 v) { return __builtin_bit_cast(bf16x8, v); }
__device__ __forceinline__ u16 bf16_bits(float f) { return __builtin_bit_cast(u16, (__bf16)f); }

// Detect whether the harness gave us float32 (true) or bf16 (false) buffers.
// float32 read as u16 pairs: even-index words are low-mantissa bits, uniform
// random -> exponent field > 130 with p~0.49.  bf16 N(0,1): never > 130.
__device__ __forceinline__ bool detect_f32(const void* X) {
    const u16* x16 = (const u16*)X;
    int lane = threadIdx.x & 63;
    int hits = 0;
#pragma unroll
    for (int i = 0; i < 4; ++i) {
        u16 v = x16[lane * 4 + i];
        int e = (v >> 7) & 0xFF;
        hits += (e > 130) ? 1 : 0;
    }
    unsigned long long m = __ballot(hits > 0);
    return __popcll(m) >= 8;
}

// Load 8 consecutive elements (element offset eoff) as bf16x8.
__device__ __forceinline__ bf16x8 load8(const void* p, size_t eoff, bool f32m) {
    if (!f32m) {
        return as_bf16x8(*(const int4*)((const u16*)p + eoff));
    } else {
        const float* f = (const float*)p + eoff;
        float4 a = *(const float4*)f;
        float4 b = *(const float4*)(f + 4);
        bf16x8 r;
        r[0] = (__bf16)a.x; r[1] = (__bf16)a.y; r[2] = (__bf16)a.z; r[3] = (__bf16)a.w;
        r[4] = (__bf16)b.x; r[5] = (__bf16)b.y; r[6] = (__bf16)b.z; r[7] = (__bf16)b.w;
        return r;
    }
}

// ---------------- 64x64 tile transpose (weights -> bf16) --------------------
__global__ __launch_bounds__(256) void transpose64(const void* __restrict__ in,
                                                   u16* __restrict__ out,
                                                   const void* __restrict__ Xdet,
                                                   int R, int C) {
    bool f32m = detect_f32(Xdet);
    __shared__ alignas(16) u16 T[64][TS];
    int r0 = blockIdx.y * 64, c0 = blockIdx.x * 64;
    int tr = threadIdx.x >> 3, tc8 = threadIdx.x & 7;
    bf16x8 v0 = load8(in, (size_t)(r0 + tr) * C + c0 + tc8 * 8, f32m);
    bf16x8 v1 = load8(in, (size_t)(r0 + tr + 32) * C + c0 + tc8 * 8, f32m);
    *(int4*)&T[tr][tc8 * 8]      = __builtin_bit_cast(int4, v0);
    *(int4*)&T[tr + 32][tc8 * 8] = __builtin_bit_cast(int4, v1);
    __syncthreads();
    for (int half = 0; half < 2; ++half) {
        int cr = tr + half * 32;
        u16 tmp[8];
#pragma unroll
        for (int i = 0; i < 8; ++i) tmp[i] = T[tc8 * 8 + i][cr];
        *(int4*)(out + (size_t)(c0 + cr) * R + r0 + tc8 * 8) = *(int4*)tmp;
    }
}

// ---------------- 64x64-tile bf16 MFMA GEMM: C = A * Bt^T -------------------
// A: [M][K] (dtype per a_mode), Bt: [N][K] bf16, C per c_mode.
// vt_mode==1 writes C in V^T layout [bh][d][t].
__global__ __launch_bounds__(256) void gemm_bt(const void* __restrict__ A,
                                               const u16* __restrict__ Bt,
                                               void* __restrict__ C,
                                               const void* __restrict__ Xdet,
                                               int M, int N, int K,
                                               int vt_mode, int a_mode, int c_mode) {
    bool f32m = detect_f32(Xdet);
    bool a32 = a_mode && f32m;
    bool c32 = c_mode && f32m;
    __shared__ alignas(16) u16 As[64 * TS];
    __shared__ alignas(16) u16 Bs[64 * TS];
    int tid = threadIdx.x;
    int wave = tid >> 6, lane = tid & 63, quad = lane >> 4, l16 = lane & 15;
    int m0 = blockIdx.x * 64, n0 = blockIdx.y * 64;
    int r_row = tid >> 3, r_c8 = tid & 7;

    f32x4 acc[4] = {};

    for (int k0 = 0; k0 < K; k0 += 64) {
        __syncthreads();
        bf16x8 a0 = load8(A, (size_t)(m0 + r_row) * K + k0 + r_c8 * 8, a32);
        bf16x8 a1 = load8(A, (size_t)(m0 + r_row + 32) * K + k0 + r_c8 * 8, a32);
        *(int4*)(As + r_row * TS + r_c8 * 8)        = __builtin_bit_cast(int4, a0);
        *(int4*)(As + (r_row + 32) * TS + r_c8 * 8) = __builtin_bit_cast(int4, a1);
        *(int4*)(Bs + r_row * TS + r_c8 * 8) =
            *((const int4*)(Bt + (size_t)(n0 + r_row) * K + k0) + r_c8);
        *(int4*)(Bs + (r_row + 32) * TS + r_c8 * 8) =
            *((const int4*)(Bt + (size_t)(n0 + r_row + 32) * K + k0) + r_c8);
        __syncthreads();
#pragma unroll
        for (int ks = 0; ks < 2; ++ks) {
            bf16x8 a = as_bf16x8(*(const int4*)(As + (wave * 16 + l16) * TS + ks * 32 + quad * 8));
#pragma unroll
            for (int nt = 0; nt < 4; ++nt) {
                bf16x8 b = as_bf16x8(*(const int4*)(Bs + (nt * 16 + l16) * TS + ks * 32 + quad * 8));
                acc[nt] = __builtin_amdgcn_mfma_f32_16x16x32_bf16(a, b, acc[nt], 0, 0, 0);
            }
        }
    }
#pragma unroll
    for (int nt = 0; nt < 4; ++nt) {
#pragma unroll
        for (int r = 0; r < 4; ++r) {
            int m = m0 + wave * 16 + quad * 4 + r;
            int n = n0 + nt * 16 + l16;
            float f = acc[nt][r];
            if (!vt_mode) {
                if (c32) ((float*)C)[(size_t)m * N + n] = f;
                else     ((u16*)C)[(size_t)m * N + n] = bf16_bits(f);
            } else {
                int b = m >> 11, t = m & 2047;
                int bh = (b << 4) | (n >> 6), d = n & 63;
                ((u16*)C)[(((size_t)bh * 64 + d) << 11) + t] = bf16_bits(f);
            }
        }
    }
}

// ---------------- flash attention (causal), 64 q-rows per block -------------
// Q,K: [4096][1024] bf16; Vt: [32][64][2048] bf16; Ab: [4096][1024] bf16.
__global__ __launch_bounds__(256) void attn_kernel(const u16* __restrict__ Qb,
                                                   const u16* __restrict__ Kb,
                                                   const u16* __restrict__ Vt,
                                                   u16* __restrict__ Ab) {
    __shared__ alignas(16) u16 Ks[64 * TS];
    __shared__ alignas(16) u16 Vs[64 * TS];
    __shared__ alignas(16) u16 Ps[64 * TS];

    int tid = threadIdx.x;
    int wave = tid >> 6, lane = tid & 63, quad = lane >> 4, l16 = lane & 15;
    int jq = blockIdx.x;                 // q tile index, q0 = 64*jq
    int bh = blockIdx.y;
    int b = bh >> 4, h = bh & 15;
    int q0 = jq * 64;
    int r_row = tid >> 3, r_c8 = tid & 7;

    // Q fragments for this wave's 16-row strip (A-operand layout)
    const u16* qrow = Qb + (size_t)(b * 2048 + q0 + wave * 16 + l16) * 1024 + h * 64;
    bf16x8 qa0 = as_bf16x8(*(const int4*)(qrow + quad * 8));
    bf16x8 qa1 = as_bf16x8(*(const int4*)(qrow + 32 + quad * 8));

    f32x4 o[4] = {};
    float mrow[4], lrow[4];
#pragma unroll
    for (int r = 0; r < 4; ++r) { mrow[r] = NEG_INF; lrow[r] = 0.0f; }

    const u16* kbase = Kb + (size_t)(b * 2048) * 1024 + h * 64;
    const u16* vbase = Vt + (size_t)bh * 64 * 2048;

    for (int j = 0; j <= jq; ++j) {
        __syncthreads();
        // stage K tile [kv 64][d 64] and V^T tile [d 64][kv 64]
        *(int4*)(Ks + r_row * TS + r_c8 * 8) =
            *((const int4*)(kbase + (size_t)(j * 64 + r_row) * 1024) + r_c8);
        *(int4*)(Ks + (r_row + 32) * TS + r_c8 * 8) =
            *((const int4*)(kbase + (size_t)(j * 64 + r_row + 32) * 1024) + r_c8);
        *(int4*)(Vs + r_row * TS + r_c8 * 8) =
            *((const int4*)(vbase + (size_t)r_row * 2048 + j * 64) + r_c8);
        *(int4*)(Vs + (r_row + 32) * TS + r_c8 * 8) =
            *((const int4*)(vbase + (size_t)(r_row + 32) * 2048 + j * 64) + r_c8);
        __syncthreads();

        // S = (Q K^T) / 8
        f32x4 s[4];
#pragma unroll
        for (int nt = 0; nt < 4; ++nt) {
            f32x4 a = {};
            bf16x8 b0 = as_bf16x8(*(const int4*)(Ks + (nt * 16 + l16) * TS + quad * 8));
            a = __builtin_amdgcn_mfma_f32_16x16x32_bf16(qa0, b0, a, 0, 0, 0);
            bf16x8 b1 = as_bf16x8(*(const int4*)(Ks + (nt * 16 + l16) * TS + 32 + quad * 8));
            a = __builtin_amdgcn_mfma_f32_16x16x32_bf16(qa1, b1, a, 0, 0, 0);
            s[nt] = a * 0.125f;
        }
        if (j == jq) {  // causal mask on the diagonal tile
#pragma unroll
            for (int nt = 0; nt < 4; ++nt)
#pragma unroll
                for (int r = 0; r < 4; ++r)
                    if (nt * 16 + l16 > wave * 16 + quad * 4 + r) s[nt][r] = NEG_INF;
        }

        // online softmax per q-row (rows live in 16-lane quad groups)
#pragma unroll
        for (int r = 0; r < 4; ++r) {
            float mx = fmaxf(fmaxf(s[0][r], s[1][r]), fmaxf(s[2][r], s[3][r]));
            mx = fmaxf(mx, __shfl_xor(mx, 1, 16));
            mx = fmaxf(mx, __shfl_xor(mx, 2, 16));
            mx = fmaxf(mx, __shfl_xor(mx, 4, 16));
            mx = fmaxf(mx, __shfl_xor(mx, 8, 16));
            float mnew = fmaxf(mrow[r], mx);
            float alpha = __expf(mrow[r] - mnew);
            mrow[r] = mnew;
            float psum = 0.0f;
#pragma unroll
            for (int nt = 0; nt < 4; ++nt) {
                float p = __expf(s[nt][r] - mnew);
                psum += p;
                Ps[(wave * 16 + quad * 4 + r) * TS + nt * 16 + l16] = bf16_bits(p);
                o[nt][r] *= alpha;
            }
            psum += __shfl_xor(psum, 1, 16);
            psum += __shfl_xor(psum, 2, 16);
            psum += __shfl_xor(psum, 4, 16);
            psum += __shfl_xor(psum, 8, 16);
            lrow[r] = lrow[r] * alpha + psum;
        }
        __syncthreads();   // make P visible (safety; intra-wave rows anyway)

        // O += P V   (P read back in A-operand layout)
#pragma unroll
        for (int ks = 0; ks < 2; ++ks) {
            bf16x8 pa = as_bf16x8(*(const int4*)(Ps + (wave * 16 + l16) * TS + ks * 32 + quad * 8));
#pragma unroll
            for (int nt = 0; nt < 4; ++nt) {
                bf16x8 vb = as_bf16x8(*(const int4*)(Vs + (nt * 16 + l16) * TS + ks * 32 + quad * 8));
                o[nt] = __builtin_amdgcn_mfma_f32_16x16x32_bf16(pa, vb, o[nt], 0, 0, 0);
            }
        }
    }

    // epilogue: O / l  -> A in [token][h*64+d] layout (bf16)
    u16* arow = Ab + (size_t)(b * 2048 + q0 + wave * 16) * 1024 + h * 64;
#pragma unroll
    for (int r = 0; r < 4; ++r) {
        float inv = 1.0f / lrow[r];
#pragma unroll
        for (int nt = 0; nt < 4; ++nt)
            arow[(quad * 4 + r) * 1024 + nt * 16 + l16] = bf16_bits(o[nt][r] * inv);
    }
}

// ---------------------------------------------------------------------------
extern "C" void kernel_launch(void* const* d_in, const int* in_sizes, int n_in,
                              void* d_out, int out_size, void* d_ws, size_t ws_size,
                              hipStream_t stream) {
    (void)in_sizes; (void)n_in; (void)out_size; (void)ws_size;
    const void* X  = d_in[0];
    const void* Wq = d_in[1];
    const void* Wk = d_in[2];
    const void* Wv = d_in[3];
    const void* Wo = d_in[4];
    u16* ws16 = (u16*)d_ws;
    const size_t M1 = 1u << 20;
    u16* Wqt = ws16 + 0 * M1;
    u16* Wkt = ws16 + 1 * M1;
    u16* Wvt = ws16 + 2 * M1;
    u16* Qb  = ws16 + 4 * M1;
    u16* Kb  = ws16 + 8 * M1;
    u16* Vt  = ws16 + 12 * M1;
    u16* Wot = ws16 + 16 * M1;
    u16* Ab  = ws16 + 0 * M1;   // aliases Wq^T/Wk^T/Wv^T/pad (dead by then)

    transpose64<<<dim3(16, 16), 256, 0, stream>>>(Wq, Wqt, X, 1024, 1024);
    transpose64<<<dim3(16, 16), 256, 0, stream>>>(Wk, Wkt, X, 1024, 1024);
    transpose64<<<dim3(16, 16), 256, 0, stream>>>(Wv, Wvt, X, 1024, 1024);
    transpose64<<<dim3(16, 16), 256, 0, stream>>>(Wo, Wot, X, 1024, 1024);

    gemm_bt<<<dim3(64, 16), 256, 0, stream>>>(X, Wqt, Qb, X, 4096, 1024, 1024, 0, 1, 0);
    gemm_bt<<<dim3(64, 16), 256, 0, stream>>>(X, Wkt, Kb, X, 4096, 1024, 1024, 0, 1, 0);
    gemm_bt<<<dim3(64, 16), 256, 0, stream>>>(X, Wvt, Vt, X, 4096, 1024, 1024, 1, 1, 0);

    attn_kernel<<<dim3(32, 32), 256, 0, stream>>>(Qb, Kb, Vt, Ab);

    gemm_bt<<<dim3(64, 16), 256, 0, stream>>>(Ab, Wot, d_out, X, 4096, 1024, 1024, 0, 0, 1);
}

// Round 3
// 241.568 us; speedup vs baseline: 1.4061x; 1.4061x over previous
//
#include <hip/hip_runtime.h>
#include <hip/hip_bf16.h>

// ---------------------------------------------------------------------------
// Causal MHA forward.  B=2, T=2048, H=16, Dk=64, D=1024.
// R3: m97-style 128x128 GEMM w/ global_load_lds(16B), fused QKV projection,
//     attention q-tile 128 x kv-tile 128 (8 waves), exp2 softmax, LPT grid.
// Workspace (u16 elements, 1M = 2^20), 34 MB (same budget R2 proved):
//   [0,3M)   Wqkv^T (3 x [1024][1024])    [3M,4M) pad
//   [4M,8M)  Q  [4096][1024]   [8M,12M) K   [12M,16M) V^T [32][64][2048]
//   [16M,17M) Wo^T
//   Ab [4096][1024] aliases [0,4M) (Wqkv^T dead after QKV GEMM)
// ---------------------------------------------------------------------------

typedef unsigned short u16;
typedef __bf16 bf16x8 __attribute__((ext_vector_type(8)));
typedef float f32x4 __attribute__((ext_vector_type(4)));

#define TS 72               // K-tile LDS stride (2-way bank alias = free)
#define PS 136              // P/V-tile LDS stride (2-way alias)
#define NEG_INF (-1e30f)
#define SC_LOG2 0.1803368801f   // log2(e)/8  (exp2-domain softmax scale)

#if __has_builtin(__builtin_amdgcn_exp2f)
#define EXP2(x) __builtin_amdgcn_exp2f(x)
#else
#define EXP2(x) exp2f(x)
#endif

#define GLD_LDS16(gp, lp) __builtin_amdgcn_global_load_lds( \
    (const __attribute__((address_space(1))) void*)(gp),    \
    (__attribute__((address_space(3))) void*)(lp), 16, 0, 0)

__device__ __forceinline__ bf16x8 as_bf16x8(int4 v) { return __builtin_bit_cast(bf16x8, v); }
__device__ __forceinline__ u16 bf16_bits(float f) { return __builtin_bit_cast(u16, (__bf16)f); }

// Runtime dtype detect (see R2): f32-as-u16 low words have big exponent field.
__device__ __forceinline__ bool detect_f32(const void* X) {
    const u16* x16 = (const u16*)X;
    int lane = threadIdx.x & 63;
    int hits = 0;
#pragma unroll
    for (int i = 0; i < 4; ++i) {
        u16 v = x16[lane * 4 + i];
        hits += (((v >> 7) & 0xFF) > 130) ? 1 : 0;
    }
    return __popcll(__ballot(hits > 0)) >= 8;
}

__device__ __forceinline__ bf16x8 load8(const void* p, size_t eoff, bool f32m) {
    if (!f32m) return as_bf16x8(*(const int4*)((const u16*)p + eoff));
    const float* f = (const float*)p + eoff;
    float4 a = *(const float4*)f;
    float4 b = *(const float4*)(f + 4);
    bf16x8 r;
    r[0] = (__bf16)a.x; r[1] = (__bf16)a.y; r[2] = (__bf16)a.z; r[3] = (__bf16)a.w;
    r[4] = (__bf16)b.x; r[5] = (__bf16)b.y; r[6] = (__bf16)b.z; r[7] = (__bf16)b.w;
    return r;
}

// ---------------- all-4-weights transpose, one dispatch (z picks matrix) ----
__global__ __launch_bounds__(256) void transpose_all(const void* __restrict__ Wq,
                                                     const void* __restrict__ Wk,
                                                     const void* __restrict__ Wv,
                                                     const void* __restrict__ Wo,
                                                     u16* __restrict__ Wt3,
                                                     u16* __restrict__ Wot,
                                                     const void* __restrict__ Xdet) {
    bool f32m = detect_f32(Xdet);
    int z = blockIdx.z;
    const void* in = (z == 0) ? Wq : (z == 1) ? Wk : (z == 2) ? Wv : Wo;
    u16* out = (z < 3) ? (Wt3 + (size_t)z * (1u << 20)) : Wot;
    __shared__ alignas(16) u16 T[64][TS];
    int r0 = blockIdx.y * 64, c0 = blockIdx.x * 64;
    int tr = threadIdx.x >> 3, tc8 = threadIdx.x & 7;
    bf16x8 v0 = load8(in, (size_t)(r0 + tr) * 1024 + c0 + tc8 * 8, f32m);
    bf16x8 v1 = load8(in, (size_t)(r0 + tr + 32) * 1024 + c0 + tc8 * 8, f32m);
    *(int4*)&T[tr][tc8 * 8]      = __builtin_bit_cast(int4, v0);
    *(int4*)&T[tr + 32][tc8 * 8] = __builtin_bit_cast(int4, v1);
    __syncthreads();
    for (int half = 0; half < 2; ++half) {
        int cr = tr + half * 32;
        u16 tmp[8];
#pragma unroll
        for (int i = 0; i < 8; ++i) tmp[i] = T[tc8 * 8 + i][cr];
        *(int4*)(out + (size_t)(c0 + cr) * 1024 + r0 + tc8 * 8) = *(int4*)tmp;
    }
}

// ---------------- 128x128-tile bf16 MFMA GEMM (m97 structure) ---------------
// A: [4096][1024]; Bt: [N][1024] bf16 (pre-transposed). qkv_mode=1: N=3072,
// writes Q/K/Vt; else writes Cout [4096][1024] (dtype per detect).
__global__ __launch_bounds__(256) void gemm128(const void* __restrict__ A,
                                               const u16* __restrict__ Bt,
                                               u16* __restrict__ Cq, u16* __restrict__ Ck,
                                               u16* __restrict__ Cv, void* __restrict__ Cout,
                                               const void* __restrict__ Xdet,
                                               int qkv_mode, int a_mode) {
    bool f32m = detect_f32(Xdet);
    bool a32 = a_mode && f32m;
    __shared__ alignas(16) u16 As[128 * 64];
    __shared__ alignas(16) u16 Bs[128 * 64];
    const int K = 1024;
    int tid = threadIdx.x, wave = tid >> 6, lane = tid & 63;
    int quad = lane >> 4, l16 = lane & 15;
    int wrow = wave >> 1, wcol = wave & 1;
    int m0 = blockIdx.x * 128, n0 = blockIdx.y * 128;
    const u16* A16 = (const u16*)A;

    f32x4 acc[4][4] = {};

    for (int k0 = 0; k0 < K; k0 += 64) {
        __syncthreads();
        if (!a32) {
#pragma unroll
            for (int i = 0; i < 4; ++i) {
                int row = (wave * 4 + i) * 8 + (lane >> 3);
                int col = (lane & 7) * 8;
                GLD_LDS16(A16 + (size_t)(m0 + row) * K + k0 + col, As + (wave * 4 + i) * 512);
                GLD_LDS16(Bt  + (size_t)(n0 + row) * K + k0 + col, Bs + (wave * 4 + i) * 512);
            }
        } else {
#pragma unroll
            for (int i = 0; i < 4; ++i) {
                int row = i * 32 + (tid >> 3), c8 = tid & 7;
                bf16x8 av = load8(A, (size_t)(m0 + row) * K + k0 + c8 * 8, true);
                *(int4*)(As + row * 64 + c8 * 8) = __builtin_bit_cast(int4, av);
                *(int4*)(Bs + row * 64 + c8 * 8) =
                    *((const int4*)(Bt + (size_t)(n0 + row) * K + k0) + c8);
            }
        }
        __syncthreads();
#pragma unroll
        for (int ks = 0; ks < 2; ++ks) {
            bf16x8 af[4], bfr[4];
#pragma unroll
            for (int i = 0; i < 4; ++i)
                af[i] = as_bf16x8(*(const int4*)(As + (wrow * 64 + i * 16 + l16) * 64 + ks * 32 + quad * 8));
#pragma unroll
            for (int j = 0; j < 4; ++j)
                bfr[j] = as_bf16x8(*(const int4*)(Bs + (wcol * 64 + j * 16 + l16) * 64 + ks * 32 + quad * 8));
#pragma unroll
            for (int i = 0; i < 4; ++i)
#pragma unroll
                for (int j = 0; j < 4; ++j)
                    acc[i][j] = __builtin_amdgcn_mfma_f32_16x16x32_bf16(af[i], bfr[j], acc[i][j], 0, 0, 0);
        }
    }

#pragma unroll
    for (int i = 0; i < 4; ++i)
#pragma unroll
        for (int j = 0; j < 4; ++j)
#pragma unroll
            for (int r = 0; r < 4; ++r) {
                int m = m0 + wrow * 64 + i * 16 + quad * 4 + r;
                int n = n0 + wcol * 64 + j * 16 + l16;
                float f = acc[i][j][r];
                if (qkv_mode) {
                    if (n < 1024)       Cq[(size_t)m * 1024 + n] = bf16_bits(f);
                    else if (n < 2048)  Ck[(size_t)m * 1024 + n - 1024] = bf16_bits(f);
                    else {
                        int n2 = n - 2048;
                        int bh = ((m >> 11) << 4) | (n2 >> 6), d = n2 & 63, t = m & 2047;
                        Cv[(((size_t)bh * 64 + d) << 11) + t] = bf16_bits(f);
                    }
                } else {
                    if (f32m) ((float*)Cout)[(size_t)m * 1024 + n] = f;
                    else      ((u16*)Cout)[(size_t)m * 1024 + n] = bf16_bits(f);
                }
            }
}

// ---------------- flash attention: q-tile 128 x kv-tile 128, 8 waves --------
__global__ __launch_bounds__(512, 4) void attn_kernel(const u16* __restrict__ Qb,
                                                      const u16* __restrict__ Kb,
                                                      const u16* __restrict__ Vt,
                                                      u16* __restrict__ Ab) {
    __shared__ alignas(16) u16 Ks[128 * TS];   // [kv 128][d 64]
    __shared__ alignas(16) u16 Vs[64 * PS];    // [d 64][t 128]
    __shared__ alignas(16) u16 Ps[128 * PS];   // [q 128][kv 128]

    int tid = threadIdx.x, wave = tid >> 6, lane = tid & 63;
    int quad = lane >> 4, l16 = lane & 15;
    int bh = blockIdx.x;                 // x fastest => heavy-J blocks first
    int J = 15 - blockIdx.y;             // LPT: heaviest q-tiles dispatch first
    int b = bh >> 4, h = bh & 15;
    int q0 = J * 128;
    int sr = tid >> 3, sc8 = tid & 7;

    // per-wave Q fragments (16 q-rows), direct from global
    const u16* qrow = Qb + (size_t)(b * 2048 + q0 + wave * 16 + l16) * 1024 + h * 64;
    bf16x8 qa0 = as_bf16x8(*(const int4*)(qrow + quad * 8));
    bf16x8 qa1 = as_bf16x8(*(const int4*)(qrow + 32 + quad * 8));

    f32x4 o[4] = {};
    float mrow[4], lrow[4];
#pragma unroll
    for (int r = 0; r < 4; ++r) { mrow[r] = NEG_INF; lrow[r] = 0.0f; }

    const u16* kbase = Kb + (size_t)(b * 2048) * 1024 + h * 64;
    const u16* vbase = Vt + (size_t)bh * 64 * 2048;

    for (int j2 = 0; j2 <= J; ++j2) {
        int t0 = j2 * 128;
        __syncthreads();
        *(int4*)(Ks + sr * TS + sc8 * 8) =
            *((const int4*)(kbase + (size_t)(t0 + sr) * 1024) + sc8);
        *(int4*)(Ks + (sr + 64) * TS + sc8 * 8) =
            *((const int4*)(kbase + (size_t)(t0 + sr + 64) * 1024) + sc8);
        *(int4*)(Vs + sr * PS + sc8 * 8) =
            *((const int4*)(vbase + (size_t)sr * 2048 + t0) + sc8);
        *(int4*)(Vs + sr * PS + 64 + sc8 * 8) =
            *((const int4*)(vbase + (size_t)sr * 2048 + t0 + 64) + sc8);
        __syncthreads();

        bool diag = (j2 == J);
        int ntc = diag ? ((wave & ~1) + 2) : 8;   // computed kv-16-tiles (ks granular)

        // S tiles (exp2 domain)
        f32x4 s[8];
#pragma unroll
        for (int nt = 0; nt < 8; ++nt) {
            if (nt >= ntc) continue;
            if (diag && nt > wave) {              // fully-masked filler tile
                s[nt][0] = NEG_INF; s[nt][1] = NEG_INF; s[nt][2] = NEG_INF; s[nt][3] = NEG_INF;
                continue;
            }
            f32x4 a = {};
            bf16x8 b0 = as_bf16x8(*(const int4*)(Ks + (nt * 16 + l16) * TS + quad * 8));
            a = __builtin_amdgcn_mfma_f32_16x16x32_bf16(qa0, b0, a, 0, 0, 0);
            bf16x8 b1 = as_bf16x8(*(const int4*)(Ks + (nt * 16 + l16) * TS + 32 + quad * 8));
            a = __builtin_amdgcn_mfma_f32_16x16x32_bf16(qa1, b1, a, 0, 0, 0);
            a = a * SC_LOG2;
            if (diag && nt == wave) {             // diagonal 16x16: element mask
#pragma unroll
                for (int r = 0; r < 4; ++r)
                    if (l16 > quad * 4 + r) a[r] = NEG_INF;
            }
            s[nt] = a;
        }

        // online softmax (base-2), rows in 16-lane quad groups
#pragma unroll
        for (int r = 0; r < 4; ++r) {
            float mx = NEG_INF;
#pragma unroll
            for (int nt = 0; nt < 8; ++nt)
                if (nt < ntc) mx = fmaxf(mx, s[nt][r]);
            mx = fmaxf(mx, __shfl_xor(mx, 1, 16));
            mx = fmaxf(mx, __shfl_xor(mx, 2, 16));
            mx = fmaxf(mx, __shfl_xor(mx, 4, 16));
            mx = fmaxf(mx, __shfl_xor(mx, 8, 16));
            float mnew = fmaxf(mrow[r], mx);
            float alpha = EXP2(mrow[r] - mnew);
            mrow[r] = mnew;
            float psum = 0.0f;
            int prow = (wave * 16 + quad * 4 + r) * PS;
#pragma unroll
            for (int nt = 0; nt < 8; ++nt) {
                if (nt >= ntc) continue;
                float p = EXP2(s[nt][r] - mnew);
                psum += p;
                Ps[prow + nt * 16 + l16] = bf16_bits(p);
            }
            psum += __shfl_xor(psum, 1, 16);
            psum += __shfl_xor(psum, 2, 16);
            psum += __shfl_xor(psum, 4, 16);
            psum += __shfl_xor(psum, 8, 16);
            lrow[r] = lrow[r] * alpha + psum;
#pragma unroll
            for (int d4 = 0; d4 < 4; ++d4) o[d4][r] *= alpha;
        }

        // O += P V   (P re-read in A-layout; intra-wave rows, no barrier)
        int ksm = ntc >> 1;
#pragma unroll
        for (int ks = 0; ks < 4; ++ks) {
            if (ks >= ksm) continue;
            bf16x8 pa = as_bf16x8(*(const int4*)(Ps + (wave * 16 + l16) * PS + ks * 32 + quad * 8));
#pragma unroll
            for (int d4 = 0; d4 < 4; ++d4) {
                bf16x8 vb = as_bf16x8(*(const int4*)(Vs + (d4 * 16 + l16) * PS + ks * 32 + quad * 8));
                o[d4] = __builtin_amdgcn_mfma_f32_16x16x32_bf16(pa, vb, o[d4], 0, 0, 0);
            }
        }
    }

    // epilogue: O / l -> A [token][h*64+d] bf16
    u16* arow = Ab + (size_t)(b * 2048 + q0 + wave * 16) * 1024 + h * 64;
#pragma unroll
    for (int r = 0; r < 4; ++r) {
        float inv = 1.0f / lrow[r];
#pragma unroll
        for (int d4 = 0; d4 < 4; ++d4)
            arow[(quad * 4 + r) * 1024 + d4 * 16 + l16] = bf16_bits(o[d4][r] * inv);
    }
}

// ---------------------------------------------------------------------------
extern "C" void kernel_launch(void* const* d_in, const int* in_sizes, int n_in,
                              void* d_out, int out_size, void* d_ws, size_t ws_size,
                              hipStream_t stream) {
    (void)in_sizes; (void)n_in; (void)out_size; (void)ws_size;
    const void* X  = d_in[0];
    const void* Wq = d_in[1];
    const void* Wk = d_in[2];
    const void* Wv = d_in[3];
    const void* Wo = d_in[4];
    u16* ws16 = (u16*)d_ws;
    const size_t M1 = 1u << 20;
    u16* Wt3 = ws16 + 0 * M1;        // [3M) Wq^T|Wk^T|Wv^T concat
    u16* Qb  = ws16 + 4 * M1;
    u16* Kb  = ws16 + 8 * M1;
    u16* Vt  = ws16 + 12 * M1;
    u16* Wot = ws16 + 16 * M1;
    u16* Ab  = ws16 + 0 * M1;        // aliases Wt3 (dead after QKV GEMM)

    transpose_all<<<dim3(16, 16, 4), 256, 0, stream>>>(Wq, Wk, Wv, Wo, Wt3, Wot, X);
    gemm128<<<dim3(32, 24), 256, 0, stream>>>(X, Wt3, Qb, Kb, Vt, nullptr, X, 1, 1);
    attn_kernel<<<dim3(32, 16), 512, 0, stream>>>(Qb, Kb, Vt, Ab);
    gemm128<<<dim3(32, 8), 256, 0, stream>>>(Ab, Wot, nullptr, nullptr, nullptr, d_out, X, 0, 0);
}

// Round 5
// 221.154 us; speedup vs baseline: 1.5358x; 1.0923x over previous
//
#include <hip/hip_runtime.h>
#include <hip/hip_bf16.h>

// ---------------------------------------------------------------------------
// Causal MHA forward.  B=2, T=2048, H=16, Dk=64, D=1024.  Inputs CONFIRMED
// float32 (R4 NaN fired only in the f32 staging path); internal pipeline bf16.
// R5: R4's 64x128 residency-tuned GEMM with the a32 staging bug fixed
//     (As rows 32-63 were never written; Bs now staged via global_load_lds).
// Workspace (u16 elements, 1M = 2^20), 34 MB:
//   [0,3M)   Wqkv^T (3 x [1024][1024])    [3M,4M) pad
//   [4M,8M)  Q  [4096][1024]   [8M,12M) K   [12M,16M) V^T [32][64][2048]
//   [16M,17M) Wo^T
//   Ab [4096][1024] aliases [0,4M) (Wqkv^T dead after QKV GEMM)
// ---------------------------------------------------------------------------

typedef unsigned short u16;
typedef __bf16 bf16x8 __attribute__((ext_vector_type(8)));
typedef float f32x4 __attribute__((ext_vector_type(4)));

#define TS 72               // K-tile LDS stride (2-way bank alias = free)
#define PS 136              // P/V-tile LDS stride
#define NEG_INF (-1e30f)
#define SC_LOG2 0.1803368801f   // log2(e)/8  (exp2-domain softmax scale)

#if __has_builtin(__builtin_amdgcn_exp2f)
#define EXP2(x) __builtin_amdgcn_exp2f(x)
#else
#define EXP2(x) exp2f(x)
#endif

#define GLD_LDS16(gp, lp) __builtin_amdgcn_global_load_lds( \
    (const __attribute__((address_space(1))) void*)(gp),    \
    (__attribute__((address_space(3))) void*)(lp), 16, 0, 0)

__device__ __forceinline__ bf16x8 as_bf16x8(int4 v) { return __builtin_bit_cast(bf16x8, v); }
__device__ __forceinline__ u16 bf16_bits(float f) { return __builtin_bit_cast(u16, (__bf16)f); }

// Runtime dtype detect: f32-as-u16 low words have big exponent fields.
__device__ __forceinline__ bool detect_f32(const void* X) {
    const u16* x16 = (const u16*)X;
    int lane = threadIdx.x & 63;
    int hits = 0;
#pragma unroll
    for (int i = 0; i < 4; ++i) {
        u16 v = x16[lane * 4 + i];
        hits += (((v >> 7) & 0xFF) > 130) ? 1 : 0;
    }
    return __popcll(__ballot(hits > 0)) >= 8;
}

__device__ __forceinline__ bf16x8 load8(const void* p, size_t eoff, bool f32m) {
    if (!f32m) return as_bf16x8(*(const int4*)((const u16*)p + eoff));
    const float* f = (const float*)p + eoff;
    float4 a = *(const float4*)f;
    float4 b = *(const float4*)(f + 4);
    bf16x8 r;
    r[0] = (__bf16)a.x; r[1] = (__bf16)a.y; r[2] = (__bf16)a.z; r[3] = (__bf16)a.w;
    r[4] = (__bf16)b.x; r[5] = (__bf16)b.y; r[6] = (__bf16)b.z; r[7] = (__bf16)b.w;
    return r;
}

// ---------------- all-4-weights transpose, one dispatch (z picks matrix) ----
__global__ __launch_bounds__(256) void transpose_all(const void* __restrict__ Wq,
                                                     const void* __restrict__ Wk,
                                                     const void* __restrict__ Wv,
                                                     const void* __restrict__ Wo,
                                                     u16* __restrict__ Wt3,
                                                     u16* __restrict__ Wot,
                                                     const void* __restrict__ Xdet) {
    bool f32m = detect_f32(Xdet);
    int z = blockIdx.z;
    const void* in = (z == 0) ? Wq : (z == 1) ? Wk : (z == 2) ? Wv : Wo;
    u16* out = (z < 3) ? (Wt3 + (size_t)z * (1u << 20)) : Wot;
    __shared__ alignas(16) u16 T[64][TS];
    int r0 = blockIdx.y * 64, c0 = blockIdx.x * 64;
    int tr = threadIdx.x >> 3, tc8 = threadIdx.x & 7;
    bf16x8 v0 = load8(in, (size_t)(r0 + tr) * 1024 + c0 + tc8 * 8, f32m);
    bf16x8 v1 = load8(in, (size_t)(r0 + tr + 32) * 1024 + c0 + tc8 * 8, f32m);
    *(int4*)&T[tr][tc8 * 8]      = __builtin_bit_cast(int4, v0);
    *(int4*)&T[tr + 32][tc8 * 8] = __builtin_bit_cast(int4, v1);
    __syncthreads();
    for (int half = 0; half < 2; ++half) {
        int cr = tr + half * 32;
        u16 tmp[8];
#pragma unroll
        for (int i = 0; i < 8; ++i) tmp[i] = T[tc8 * 8 + i][cr];
        *(int4*)(out + (size_t)(c0 + cr) * 1024 + r0 + tc8 * 8) = *(int4*)tmp;
    }
}

// ---------------- 64x128-tile bf16 MFMA GEMM (residency-tuned) --------------
// A: [M][1024]; Bt: [N][1024] bf16 (pre-transposed). qkv_mode=1: N=3072,
// writes Q/K/Vt; else writes Cout (dtype per detect).
// Tile: 64m x 128n, BK=64, 4 waves (wave = 32x64 subtile).
// LDS 24 KB -> 6 blocks/CU; __launch_bounds__(256,6).
__global__ __launch_bounds__(256, 6) void gemm64(const void* __restrict__ A,
                                                 const u16* __restrict__ Bt,
                                                 u16* __restrict__ Cq, u16* __restrict__ Ck,
                                                 u16* __restrict__ Cv, void* __restrict__ Cout,
                                                 const void* __restrict__ Xdet,
                                                 int qkv_mode, int a_mode) {
    bool f32m = detect_f32(Xdet);
    bool a32 = a_mode && f32m;
    __shared__ alignas(16) u16 As[64 * 64];    // [m 64][k 64]
    __shared__ alignas(16) u16 Bs[128 * 64];   // [n 128][k 64]
    const int K = 1024;
    int tid = threadIdx.x, wave = tid >> 6, lane = tid & 63;
    int quad = lane >> 4, l16 = lane & 15;
    int wrow = wave & 1, wcol = wave >> 1;      // 2x2 wave grid: 32m x 64n each
    int m0 = blockIdx.x * 64, n0 = blockIdx.y * 128;
    const u16* A16 = (const u16*)A;

    f32x4 acc[2][4] = {};

    for (int k0 = 0; k0 < K; k0 += 64) {
        __syncthreads();
        int rlane = lane >> 3, c8l = (lane & 7) * 8;
        // Bs: always bf16, 16 chunks of 8 rows, 4 per wave, via global_load_lds
#pragma unroll
        for (int i = 0; i < 4; ++i) {
            int rc = wave * 4 + i;
            GLD_LDS16(Bt + (size_t)(n0 + rc * 8 + rlane) * K + k0 + c8l, Bs + rc * 512);
        }
        if (!a32) {
            // As: 8 chunks of 8 rows, 2 per wave
#pragma unroll
            for (int i = 0; i < 2; ++i) {
                int rc = wave * 2 + i;
                GLD_LDS16(A16 + (size_t)(m0 + rc * 8 + rlane) * K + k0 + c8l, As + rc * 512);
            }
        } else {
            // f32 A: convert-and-stage, two 32-row passes (covers rows 0..63)
            int r2 = tid >> 3, c8e = (tid & 7) * 8;
            bf16x8 a0 = load8(A, (size_t)(m0 + r2) * K + k0 + c8e, true);
            *(int4*)(As + r2 * 64 + c8e) = __builtin_bit_cast(int4, a0);
            bf16x8 a1 = load8(A, (size_t)(m0 + r2 + 32) * K + k0 + c8e, true);
            *(int4*)(As + (r2 + 32) * 64 + c8e) = __builtin_bit_cast(int4, a1);
        }
        __syncthreads();
#pragma unroll
        for (int ks = 0; ks < 2; ++ks) {
            bf16x8 af[2], bfr[4];
#pragma unroll
            for (int i = 0; i < 2; ++i)
                af[i] = as_bf16x8(*(const int4*)(As + (wrow * 32 + i * 16 + l16) * 64 + ks * 32 + quad * 8));
#pragma unroll
            for (int j = 0; j < 4; ++j)
                bfr[j] = as_bf16x8(*(const int4*)(Bs + (wcol * 64 + j * 16 + l16) * 64 + ks * 32 + quad * 8));
#pragma unroll
            for (int i = 0; i < 2; ++i)
#pragma unroll
                for (int j = 0; j < 4; ++j)
                    acc[i][j] = __builtin_amdgcn_mfma_f32_16x16x32_bf16(af[i], bfr[j], acc[i][j], 0, 0, 0);
        }
    }

#pragma unroll
    for (int i = 0; i < 2; ++i)
#pragma unroll
        for (int j = 0; j < 4; ++j)
#pragma unroll
            for (int r = 0; r < 4; ++r) {
                int m = m0 + wrow * 32 + i * 16 + quad * 4 + r;
                int n = n0 + wcol * 64 + j * 16 + l16;
                float f = acc[i][j][r];
                if (qkv_mode) {
                    if (n < 1024)       Cq[(size_t)m * 1024 + n] = bf16_bits(f);
                    else if (n < 2048)  Ck[(size_t)m * 1024 + n - 1024] = bf16_bits(f);
                    else {
                        int n2 = n - 2048;
                        int bh = ((m >> 11) << 4) | (n2 >> 6), d = n2 & 63, t = m & 2047;
                        Cv[(((size_t)bh * 64 + d) << 11) + t] = bf16_bits(f);
                    }
                } else {
                    if (f32m) ((float*)Cout)[(size_t)m * 1024 + n] = f;
                    else      ((u16*)Cout)[(size_t)m * 1024 + n] = bf16_bits(f);
                }
            }
}

// ---------------- flash attention: q-tile 128 x kv-tile 128, 8 waves --------
__global__ __launch_bounds__(512, 4) void attn_kernel(const u16* __restrict__ Qb,
                                                      const u16* __restrict__ Kb,
                                                      const u16* __restrict__ Vt,
                                                      u16* __restrict__ Ab) {
    __shared__ alignas(16) u16 Ks[128 * TS];   // [kv 128][d 64]
    __shared__ alignas(16) u16 Vs[64 * PS];    // [d 64][t 128]
    __shared__ alignas(16) u16 Ps[128 * PS];   // [q 128][kv 128]

    int tid = threadIdx.x, wave = tid >> 6, lane = tid & 63;
    int quad = lane >> 4, l16 = lane & 15;
    int bh = blockIdx.x;                 // x fastest => heavy-J blocks first
    int J = 15 - blockIdx.y;             // LPT: heaviest q-tiles dispatch first
    int b = bh >> 4, h = bh & 15;
    int q0 = J * 128;
    int sr = tid >> 3, sc8 = tid & 7;

    const u16* qrow = Qb + (size_t)(b * 2048 + q0 + wave * 16 + l16) * 1024 + h * 64;
    bf16x8 qa0 = as_bf16x8(*(const int4*)(qrow + quad * 8));
    bf16x8 qa1 = as_bf16x8(*(const int4*)(qrow + 32 + quad * 8));

    f32x4 o[4] = {};
    float mrow[4], lrow[4];
#pragma unroll
    for (int r = 0; r < 4; ++r) { mrow[r] = NEG_INF; lrow[r] = 0.0f; }

    const u16* kbase = Kb + (size_t)(b * 2048) * 1024 + h * 64;
    const u16* vbase = Vt + (size_t)bh * 64 * 2048;

    for (int j2 = 0; j2 <= J; ++j2) {
        int t0 = j2 * 128;
        __syncthreads();
        *(int4*)(Ks + sr * TS + sc8 * 8) =
            *((const int4*)(kbase + (size_t)(t0 + sr) * 1024) + sc8);
        *(int4*)(Ks + (sr + 64) * TS + sc8 * 8) =
            *((const int4*)(kbase + (size_t)(t0 + sr + 64) * 1024) + sc8);
        *(int4*)(Vs + sr * PS + sc8 * 8) =
            *((const int4*)(vbase + (size_t)sr * 2048 + t0) + sc8);
        *(int4*)(Vs + sr * PS + 64 + sc8 * 8) =
            *((const int4*)(vbase + (size_t)sr * 2048 + t0 + 64) + sc8);
        __syncthreads();

        bool diag = (j2 == J);
        int ntc = diag ? ((wave & ~1) + 2) : 8;

        f32x4 s[8];
#pragma unroll
        for (int nt = 0; nt < 8; ++nt) {
            if (nt >= ntc) continue;
            if (diag && nt > wave) {
                s[nt][0] = NEG_INF; s[nt][1] = NEG_INF; s[nt][2] = NEG_INF; s[nt][3] = NEG_INF;
                continue;
            }
            f32x4 a = {};
            bf16x8 b0 = as_bf16x8(*(const int4*)(Ks + (nt * 16 + l16) * TS + quad * 8));
            a = __builtin_amdgcn_mfma_f32_16x16x32_bf16(qa0, b0, a, 0, 0, 0);
            bf16x8 b1 = as_bf16x8(*(const int4*)(Ks + (nt * 16 + l16) * TS + 32 + quad * 8));
            a = __builtin_amdgcn_mfma_f32_16x16x32_bf16(qa1, b1, a, 0, 0, 0);
            a = a * SC_LOG2;
            if (diag && nt == wave) {
#pragma unroll
                for (int r = 0; r < 4; ++r)
                    if (l16 > quad * 4 + r) a[r] = NEG_INF;
            }
            s[nt] = a;
        }

#pragma unroll
        for (int r = 0; r < 4; ++r) {
            float mx = NEG_INF;
#pragma unroll
            for (int nt = 0; nt < 8; ++nt)
                if (nt < ntc) mx = fmaxf(mx, s[nt][r]);
            mx = fmaxf(mx, __shfl_xor(mx, 1, 16));
            mx = fmaxf(mx, __shfl_xor(mx, 2, 16));
            mx = fmaxf(mx, __shfl_xor(mx, 4, 16));
            mx = fmaxf(mx, __shfl_xor(mx, 8, 16));
            float mnew = fmaxf(mrow[r], mx);
            float alpha = EXP2(mrow[r] - mnew);
            mrow[r] = mnew;
            float psum = 0.0f;
            int prow = (wave * 16 + quad * 4 + r) * PS;
#pragma unroll
            for (int nt = 0; nt < 8; ++nt) {
                if (nt >= ntc) continue;
                float p = EXP2(s[nt][r] - mnew);
                psum += p;
                Ps[prow + nt * 16 + l16] = bf16_bits(p);
            }
            psum += __shfl_xor(psum, 1, 16);
            psum += __shfl_xor(psum, 2, 16);
            psum += __shfl_xor(psum, 4, 16);
            psum += __shfl_xor(psum, 8, 16);
            lrow[r] = lrow[r] * alpha + psum;
#pragma unroll
            for (int d4 = 0; d4 < 4; ++d4) o[d4][r] *= alpha;
        }

        int ksm = ntc >> 1;
#pragma unroll
        for (int ks = 0; ks < 4; ++ks) {
            if (ks >= ksm) continue;
            bf16x8 pa = as_bf16x8(*(const int4*)(Ps + (wave * 16 + l16) * PS + ks * 32 + quad * 8));
#pragma unroll
            for (int d4 = 0; d4 < 4; ++d4) {
                bf16x8 vb = as_bf16x8(*(const int4*)(Vs + (d4 * 16 + l16) * PS + ks * 32 + quad * 8));
                o[d4] = __builtin_amdgcn_mfma_f32_16x16x32_bf16(pa, vb, o[d4], 0, 0, 0);
            }
        }
    }

    u16* arow = Ab + (size_t)(b * 2048 + q0 + wave * 16) * 1024 + h * 64;
#pragma unroll
    for (int r = 0; r < 4; ++r) {
        float inv = 1.0f / lrow[r];
#pragma unroll
        for (int d4 = 0; d4 < 4; ++d4)
            arow[(quad * 4 + r) * 1024 + d4 * 16 + l16] = bf16_bits(o[d4][r] * inv);
    }
}

// ---------------------------------------------------------------------------
extern "C" void kernel_launch(void* const* d_in, const int* in_sizes, int n_in,
                              void* d_out, int out_size, void* d_ws, size_t ws_size,
                              hipStream_t stream) {
    (void)in_sizes; (void)n_in; (void)out_size; (void)ws_size;
    const void* X  = d_in[0];
    const void* Wq = d_in[1];
    const void* Wk = d_in[2];
    const void* Wv = d_in[3];
    const void* Wo = d_in[4];
    u16* ws16 = (u16*)d_ws;
    const size_t M1 = 1u << 20;
    u16* Wt3 = ws16 + 0 * M1;        // [3M) Wq^T|Wk^T|Wv^T concat
    u16* Qb  = ws16 + 4 * M1;
    u16* Kb  = ws16 + 8 * M1;
    u16* Vt  = ws16 + 12 * M1;
    u16* Wot = ws16 + 16 * M1;
    u16* Ab  = ws16 + 0 * M1;        // aliases Wt3 (dead after QKV GEMM)

    transpose_all<<<dim3(16, 16, 4), 256, 0, stream>>>(Wq, Wk, Wv, Wo, Wt3, Wot, X);
    gemm64<<<dim3(64, 24), 256, 0, stream>>>(X, Wt3, Qb, Kb, Vt, nullptr, X, 1, 1);
    attn_kernel<<<dim3(32, 16), 512, 0, stream>>>(Qb, Kb, Vt, Ab);
    gemm64<<<dim3(64, 8), 256, 0, stream>>>(Ab, Wot, nullptr, nullptr, nullptr, d_out, X, 0, 0);
}